// Round 2
// baseline (143.777 us; speedup 1.0000x reference)
//
#include <hip/hip_runtime.h>
#include <hip/hip_cooperative_groups.h>
#include <math.h>

namespace cg = cooperative_groups;

#define LSEQ 16384
#define DCH  1000
#define NBLK 256

// One fused cooperative kernel, 256 blocks x 256 threads.
// Phase A: per-channel complex recurrence; only Re(h[L-1]) survives.
//   h_last[d] = sum_t z^(L-1-t) x_t. Thread tid owns chunk [64*tid, 64*tid+64):
//   v_tid = sum_{k<64} z^(63-k) x[64 tid + k];  h_last = sum_tid z^(64*(255-tid)) v_tid.
//   The weight z^(64*(255-tid)) is lane-computable by squaring (no scan fold needed),
//   and only Re(w * v) needs reducing -> single-float block reduction.
// Phase B: x1[j] = relu(u . W1[j,:] + b1[j] + x[L-1]), 4 rows per block, u staged in LDS.
// Phase C: block 0: logits = x1 . Wf[i,:] + bf; softmax -> out[10].
__global__ __launch_bounds__(256) void fused_kernel(
    const float* __restrict__ x, const float* __restrict__ sz,
    const float* __restrict__ th, const float* __restrict__ W1,
    const float* __restrict__ b1, const float* __restrict__ Wf,
    const float* __restrict__ bf, float* __restrict__ out,
    float* __restrict__ u, float* __restrict__ x1) {
  const int tid = threadIdx.x;
  const int bid = blockIdx.x;
  const int lane = tid & 63;
  const int w = tid >> 6;
  cg::grid_group grid = cg::this_grid();

  __shared__ float sred[4];
  __shared__ float uL[1000];
  __shared__ float sredB[4][4];
  __shared__ float sH[4][10];

  // ---- Phase A ----
  // load this thread's 64 x values once; reuse for all channels of this block
  float xr0[64];
  {
    const float4* xp4 = reinterpret_cast<const float4*>(x + tid * 64);
#pragma unroll
    for (int m = 0; m < 16; ++m) {
      float4 v4 = xp4[m];
      xr0[4 * m + 0] = v4.x; xr0[4 * m + 1] = v4.y;
      xr0[4 * m + 2] = v4.z; xr0[4 * m + 3] = v4.w;
    }
  }

  for (int d = bid; d < DCH; d += NBLK) {
    const float r  = expf(-expf(sz[d]));
    const float tv = th[d];
    const float zr = r * cosf(tv);
    const float zi = r * sinf(tv);

    float vr = 0.f, vi = 0.f;
#pragma unroll
    for (int k = 0; k < 64; ++k) {
      float xv = xr0[k];
      float nvr = fmaf(zr, vr, fmaf(-zi, vi, xv));
      float nvi = fmaf(zr, vi, zi * vr);
      vr = nvr; vi = nvi;
    }

    // weight w = z^(64*(255-tid)): 6 squarings -> z^64, then 8-bit binary exp
    float br = zr, bi = zi;
#pragma unroll
    for (int k = 0; k < 6; ++k) { float t = br * br - bi * bi; bi = 2.f * br * bi; br = t; }
    float wr = 1.f, wi = 0.f;
    const int e = 255 - tid;
#pragma unroll
    for (int k = 0; k < 8; ++k) {
      float nr = wr * br - wi * bi;
      float ni = wr * bi + wi * br;
      bool bit = (e >> k) & 1;
      wr = bit ? nr : wr;
      wi = bit ? ni : wi;
      if (k < 7) { float t = br * br - bi * bi; bi = 2.f * br * bi; br = t; }
    }

    float s = wr * vr - wi * vi;  // Re(w * v)
#pragma unroll
    for (int o = 32; o > 0; o >>= 1) s += __shfl_xor(s, o);
    if (lane == 0) sred[w] = s;
    __syncthreads();
    if (tid == 0) u[d] = sred[0] + sred[1] + sred[2] + sred[3];
    __syncthreads();
  }

  grid.sync();

  // ---- Phase B ----
  const float xlast = x[LSEQ - 1];
  if (tid < 250) reinterpret_cast<float4*>(uL)[tid] = reinterpret_cast<const float4*>(u)[tid];
  __syncthreads();

  float accs[4] = {0.f, 0.f, 0.f, 0.f};
#pragma unroll
  for (int k = 0; k < 4; ++k) {
    const int j = bid + NBLK * k;
    if (j < DCH && tid < 250) {
      const float4* wrow = reinterpret_cast<const float4*>(W1 + (size_t)j * DCH);
      float4 w4 = wrow[tid];
      float4 u4 = reinterpret_cast<const float4*>(uL)[tid];
      accs[k] = fmaf(w4.x, u4.x, fmaf(w4.y, u4.y, fmaf(w4.z, u4.z, w4.w * u4.w)));
    }
  }
#pragma unroll
  for (int k = 0; k < 4; ++k) {
#pragma unroll
    for (int o = 32; o > 0; o >>= 1) accs[k] += __shfl_xor(accs[k], o);
  }
  if (lane == 0) {
#pragma unroll
    for (int k = 0; k < 4; ++k) sredB[k][w] = accs[k];
  }
  __syncthreads();
  if (tid < 4) {
    const int j = bid + NBLK * tid;
    if (j < DCH) {
      float t = sredB[tid][0] + sredB[tid][1] + sredB[tid][2] + sredB[tid][3];
      x1[j] = fmaxf(t + b1[j] + xlast, 0.f);
    }
  }

  grid.sync();

  // ---- Phase C (block 0 only) ----
  if (bid == 0) {
    float part[10];
#pragma unroll
    for (int i = 0; i < 10; ++i) part[i] = 0.f;
    for (int dd = tid; dd < DCH; dd += 256) {
      float xv = x1[dd];
#pragma unroll
      for (int i = 0; i < 10; ++i) part[i] = fmaf(xv, Wf[i * DCH + dd], part[i]);
    }
#pragma unroll
    for (int i = 0; i < 10; ++i) {
#pragma unroll
      for (int o = 32; o > 0; o >>= 1) part[i] += __shfl_xor(part[i], o);
    }
    if (lane == 0) {
#pragma unroll
      for (int i = 0; i < 10; ++i) sH[w][i] = part[i];
    }
    __syncthreads();
    if (tid == 0) {
      float logits[10];
      float m = -1e30f;
#pragma unroll
      for (int i = 0; i < 10; ++i) {
        logits[i] = sH[0][i] + sH[1][i] + sH[2][i] + sH[3][i] + bf[i];
        m = fmaxf(m, logits[i]);
      }
      float ssum = 0.f;
#pragma unroll
      for (int i = 0; i < 10; ++i) { logits[i] = expf(logits[i] - m); ssum += logits[i]; }
      float inv = 1.f / ssum;
#pragma unroll
      for (int i = 0; i < 10; ++i) out[i] = logits[i] * inv;
    }
  }
}

extern "C" void kernel_launch(void* const* d_in, const int* in_sizes, int n_in,
                              void* d_out, int out_size, void* d_ws, size_t ws_size,
                              hipStream_t stream) {
  const float* x  = (const float*)d_in[0];  // [16384]
  const float* sz = (const float*)d_in[1];  // [1000]
  const float* th = (const float*)d_in[2];  // [1000]
  const float* W1 = (const float*)d_in[3];  // [1000,1000]
  const float* b1 = (const float*)d_in[4];  // [1000]
  const float* Wf = (const float*)d_in[5];  // [10,1000]
  const float* bf = (const float*)d_in[6];  // [10]
  float* out = (float*)d_out;               // [10]

  float* u  = (float*)d_ws;                 // [1000] Re(h_last)
  float* x1 = u + 1024;                     // [1000] relu'd hidden

  void* args[] = {(void*)&x, (void*)&sz, (void*)&th, (void*)&W1, (void*)&b1,
                  (void*)&Wf, (void*)&bf, (void*)&out, (void*)&u, (void*)&x1};
  hipLaunchCooperativeKernel((void*)fused_kernel, dim3(NBLK), dim3(256), args, 0, stream);
}

// Round 3
// 82.339 us; speedup vs baseline: 1.7462x; 1.7462x over previous
//
#include <hip/hip_runtime.h>
#include <math.h>

#define LSEQ 16384
#define DCH  1000

// ---------------------------------------------------------------------------
// Kernel A: per-channel complex recurrence; only Re(h[L-1]) is needed.
//   h_last[d] = sum_t z^(L-1-t) x_t
// 250 blocks x 256 threads; block b handles channels 4b..4b+3.
// x (64 KB) staged in LDS with XOR swizzle: element (t,k) -> xs[64t + (k^(t&31))]
//   - staging writes: conflict-free (within-group 2-way max, which is free)
//   - chain reads (fixed k, lanes t): banks (k^(t&31))&31 distinct -> free
// Thread tid owns timesteps [64*tid, 64*tid+64); runs 4 independent chains
// (4-way ILP). Chunk weight z^(64*(255-tid)) by 6 squarings + 8-bit binexp
// (numerically validated in round 2). Only Re(w*v) is block-reduced.
// ---------------------------------------------------------------------------
__global__ __launch_bounds__(256) void scan_last_kernel(
    const float* __restrict__ x, const float* __restrict__ sz,
    const float* __restrict__ th, float* __restrict__ u) {
  __shared__ float xs[64 * 256];  // exactly 64 KB; reused for reduction scratch
  const int tid = threadIdx.x;
  const int bid = blockIdx.x;
  const int lane = tid & 63;
  const int w = tid >> 6;
  const int d0 = bid * 4;

  // ---- stage x into LDS (swizzled) ----
  const float4* x4 = reinterpret_cast<const float4*>(x);
#pragma unroll
  for (int i = 0; i < 16; ++i) {
    const int idx4 = tid + 256 * i;       // coalesced
    float4 v = x4[idx4];
    const int t = idx4 >> 4;              // row (owning thread)
    const int kb = (idx4 & 15) * 4;       // k base
    const int sw = t & 31;
    xs[64 * t + ((kb + 0) ^ sw)] = v.x;
    xs[64 * t + ((kb + 1) ^ sw)] = v.y;
    xs[64 * t + ((kb + 2) ^ sw)] = v.z;
    xs[64 * t + ((kb + 3) ^ sw)] = v.w;
  }

  // ---- per-channel decay constants (each thread computes all 4; cheap) ----
  float zr[4], zi[4];
#pragma unroll
  for (int c = 0; c < 4; ++c) {
    const float r = expf(-expf(sz[d0 + c]));
    const float tv = th[d0 + c];
    zr[c] = r * cosf(tv);
    zi[c] = r * sinf(tv);
  }

  __syncthreads();

  // ---- 64-step chains, 4 channels interleaved ----
  float vr[4] = {0.f, 0.f, 0.f, 0.f}, vi[4] = {0.f, 0.f, 0.f, 0.f};
  const int rowbase = 64 * tid;
  const int sw = tid & 31;
#pragma unroll
  for (int k = 0; k < 64; ++k) {
    const float xv = xs[rowbase + (k ^ sw)];
#pragma unroll
    for (int c = 0; c < 4; ++c) {
      const float ovr = vr[c];
      vr[c] = fmaf(zr[c], ovr, fmaf(-zi[c], vi[c], xv));
      vi[c] = fmaf(zr[c], vi[c], zi[c] * ovr);
    }
  }

  // ---- chunk weight w_c = z_c^(64*(255-tid)); s_c = Re(w_c * v_c) ----
  float s[4];
  const int e = 255 - tid;
#pragma unroll
  for (int c = 0; c < 4; ++c) {
    float br = zr[c], bi = zi[c];
#pragma unroll
    for (int k = 0; k < 6; ++k) { float t2 = br * br - bi * bi; bi = 2.f * br * bi; br = t2; }
    float wr = 1.f, wi = 0.f;
#pragma unroll
    for (int k = 0; k < 8; ++k) {
      float nr = wr * br - wi * bi;
      float ni = wr * bi + wi * br;
      const bool bit = (e >> k) & 1;
      wr = bit ? nr : wr;
      wi = bit ? ni : wi;
      if (k < 7) { float t2 = br * br - bi * bi; bi = 2.f * br * bi; br = t2; }
    }
    s[c] = wr * vr[c] - wi * vi[c];
  }

  // ---- reduce: wave shfl, then cross-wave via (reused) LDS ----
#pragma unroll
  for (int c = 0; c < 4; ++c)
#pragma unroll
    for (int o = 32; o > 0; o >>= 1) s[c] += __shfl_xor(s[c], o);

  __syncthreads();  // all chain reads done before clobbering xs[0..15]
  if (lane == 0) {
#pragma unroll
    for (int c = 0; c < 4; ++c) xs[c * 4 + w] = s[c];
  }
  __syncthreads();
  if (tid < 4)
    u[d0 + tid] = xs[tid * 4 + 0] + xs[tid * 4 + 1] + xs[tid * 4 + 2] + xs[tid * 4 + 3];
}

// ---------------------------------------------------------------------------
// Kernel B: x1[j] = relu( u . W1[j,:] + b1[j] + x[L-1] ), 4 rows per block
// ---------------------------------------------------------------------------
__global__ __launch_bounds__(256) void mv_relu_kernel(
    const float* __restrict__ u, const float* __restrict__ W1,
    const float* __restrict__ b1, const float* __restrict__ x,
    float* __restrict__ x1) {
  __shared__ float uL[1000];
  __shared__ float sred[4][4];
  const int tid = threadIdx.x;
  const int bid = blockIdx.x;
  const int lane = tid & 63;
  const int w = tid >> 6;
  const int j0 = bid * 4;

  if (tid < 250)
    reinterpret_cast<float4*>(uL)[tid] = reinterpret_cast<const float4*>(u)[tid];
  __syncthreads();

  float accs[4] = {0.f, 0.f, 0.f, 0.f};
  if (tid < 250) {
    const float4 u4 = reinterpret_cast<const float4*>(uL)[tid];
#pragma unroll
    for (int k = 0; k < 4; ++k) {
      const float4 w4 =
          reinterpret_cast<const float4*>(W1 + (size_t)(j0 + k) * DCH)[tid];
      accs[k] = fmaf(w4.x, u4.x, fmaf(w4.y, u4.y, fmaf(w4.z, u4.z, w4.w * u4.w)));
    }
  }
#pragma unroll
  for (int k = 0; k < 4; ++k)
#pragma unroll
    for (int o = 32; o > 0; o >>= 1) accs[k] += __shfl_xor(accs[k], o);
  if (lane == 0) {
#pragma unroll
    for (int k = 0; k < 4; ++k) sred[k][w] = accs[k];
  }
  __syncthreads();
  if (tid < 4) {
    const float t = sred[tid][0] + sred[tid][1] + sred[tid][2] + sred[tid][3];
    x1[j0 + tid] = fmaxf(t + b1[j0 + tid] + x[LSEQ - 1], 0.f);
  }
}

// ---------------------------------------------------------------------------
// Kernel C: logits = x1 @ Wf.T + bf ; softmax ; 10 floats out. One block.
// ---------------------------------------------------------------------------
__global__ __launch_bounds__(256) void head_softmax_kernel(
    const float* __restrict__ x1, const float* __restrict__ Wf,
    const float* __restrict__ bf, float* __restrict__ out) {
  const int tid = threadIdx.x;
  float part[10];
#pragma unroll
  for (int i = 0; i < 10; ++i) part[i] = 0.f;
  for (int dd = tid; dd < DCH; dd += 256) {
    const float xv = x1[dd];
#pragma unroll
    for (int i = 0; i < 10; ++i) part[i] = fmaf(xv, Wf[i * DCH + dd], part[i]);
  }
#pragma unroll
  for (int i = 0; i < 10; ++i)
#pragma unroll
    for (int o = 32; o > 0; o >>= 1) part[i] += __shfl_xor(part[i], o);

  __shared__ float s[4][10];
  const int lane = tid & 63, w = tid >> 6;
  if (lane == 0) {
#pragma unroll
    for (int i = 0; i < 10; ++i) s[w][i] = part[i];
  }
  __syncthreads();
  if (tid == 0) {
    float logits[10];
    float m = -1e30f;
#pragma unroll
    for (int i = 0; i < 10; ++i) {
      logits[i] = s[0][i] + s[1][i] + s[2][i] + s[3][i] + bf[i];
      m = fmaxf(m, logits[i]);
    }
    float ssum = 0.f;
#pragma unroll
    for (int i = 0; i < 10; ++i) { logits[i] = expf(logits[i] - m); ssum += logits[i]; }
    const float inv = 1.f / ssum;
#pragma unroll
    for (int i = 0; i < 10; ++i) out[i] = logits[i] * inv;
  }
}

extern "C" void kernel_launch(void* const* d_in, const int* in_sizes, int n_in,
                              void* d_out, int out_size, void* d_ws, size_t ws_size,
                              hipStream_t stream) {
  const float* x  = (const float*)d_in[0];  // [16384]
  const float* sz = (const float*)d_in[1];  // [1000]
  const float* th = (const float*)d_in[2];  // [1000]
  const float* W1 = (const float*)d_in[3];  // [1000,1000]
  const float* b1 = (const float*)d_in[4];  // [1000]
  const float* Wf = (const float*)d_in[5];  // [10,1000]
  const float* bf = (const float*)d_in[6];  // [10]
  float* out = (float*)d_out;               // [10]

  float* u  = (float*)d_ws;                 // [1000] Re(h_last)
  float* x1 = u + 1024;                     // [1000] relu'd hidden

  scan_last_kernel<<<250, 256, 0, stream>>>(x, sz, th, u);
  mv_relu_kernel<<<250, 256, 0, stream>>>(u, W1, b1, x, x1);
  head_softmax_kernel<<<1, 256, 0, stream>>>(x1, Wf, bf, out);
}